// Round 1
// baseline (461.842 us; speedup 1.0000x reference)
//
#include <hip/hip_runtime.h>

// ---------------------------------------------------------------------------
// Attention_28561532519042: GCN-projection + BN + ReLU + causal time-attention
// B2=400 (=16 batch x 25 joints), T=120, C=128, QKV_C=1536, HEADS=8, DH=64
// Pipeline:
//   K1b build_weights : fold BN scales into Wcat[1536x512] bf16, Wout bf16, bias
//   K1  transform     : Zt[48000x512] bf16 = [A_h x (384) ; x (128)] per (b,t,v)
//   K2  gemm_qkv      : QKV = relu(Wcat.Zt + bias); scatter to Q/K/V^T bf16
//   K3  attn_k        : per (b2,h): S=QK^T/8 (causal) -> softmax -> attn (fp32
//                       to d_out) -> O = P.V -> o_ws bf16
//   K4  gemm_out_k    : out = o_ws . Wout^T + out_b  (fp32 to d_out)
// ---------------------------------------------------------------------------

typedef __bf16 bf16;
typedef __bf16 bf16x8 __attribute__((ext_vector_type(8)));
typedef float  f32x4  __attribute__((ext_vector_type(4)));
typedef __attribute__((address_space(1))) const void* gptr1;
typedef __attribute__((address_space(3))) void*       lptr3;

#define GLL16(g, l) __builtin_amdgcn_global_load_lds((gptr1)(g), (lptr3)(l), 16, 0, 0)
#define MFMA16(a, b, c) __builtin_amdgcn_mfma_f32_16x16x32_bf16(a, b, c, 0, 0, 0)

// ---------------- K1b: fold BN into weights -------------------------------
__global__ __launch_bounds__(256) void build_weights(
    const float* __restrict__ conv_w, const float* __restrict__ conv_b,
    const float* __restrict__ g1, const float* __restrict__ be1,
    const float* __restrict__ mu1, const float* __restrict__ va1,
    const float* __restrict__ down_w, const float* __restrict__ down_b,
    const float* __restrict__ g2, const float* __restrict__ be2,
    const float* __restrict__ mu2, const float* __restrict__ va2,
    const float* __restrict__ out_w,
    bf16* __restrict__ wcat, bf16* __restrict__ wout, float* __restrict__ bias)
{
    int idx = blockIdx.x * 256 + threadIdx.x;
    if (idx < 1536 * 512) {
        int o = idx >> 9, k = idx & 511;
        float s, w;
        if (k < 384) {
            int h = k >> 7, c = k & 127;
            s = g1[o] * rsqrtf(va1[o] + 1e-5f);
            w = conv_w[(h * 1536 + o) * 128 + c];
        } else {
            s = g2[o] * rsqrtf(va2[o] + 1e-5f);
            w = down_w[o * 128 + (k - 384)];
        }
        wcat[idx] = (bf16)(w * s);
    }
    int i2 = idx - 1536 * 512;
    if (i2 >= 0 && i2 < 128 * 512) wout[i2] = (bf16)out_w[i2];
    int i3 = idx - (1536 * 512 + 128 * 512);
    if (i3 >= 0 && i3 < 1536) {
        int o = i3;
        float s1 = g1[o] * rsqrtf(va1[o] + 1e-5f);
        float s2 = g2[o] * rsqrtf(va2[o] + 1e-5f);
        float cb = conv_b[o] + conv_b[1536 + o] + conv_b[2 * 1536 + o];
        bias[o] = cb * s1 + be1[o] - mu1[o] * s1
                + down_b[o] * s2 + be2[o] - mu2[o] * s2;
    }
}

// ---------------- K1: build Zt[48000][512] --------------------------------
// Zt[(b*120+t)*25+v][k] : k<384 -> sum_u A[h][v][u]*x[(b,u),t,c]  (k=h*128+c)
//                         k>=384 -> x[(b,v),t,c]
__global__ __launch_bounds__(256) void transform(
    const float* __restrict__ x, const float* __restrict__ A,
    bf16* __restrict__ zt)
{
    __shared__ float xs[25][128];
    const int tid = threadIdx.x;
    const int bt = blockIdx.x;
    const int b = bt / 120, t = bt - b * 120;
    for (int i = tid; i < 25 * 128; i += 256) {
        int u = i >> 7, c = i & 127;
        xs[u][c] = x[((size_t)(b * 25 + u) * 120 + t) * 128 + c];
    }
    __syncthreads();
    const int c = tid & 127, g = tid >> 7;   // g in {0,1}, wave-uniform
    float xr[25];
    #pragma unroll
    for (int u = 0; u < 25; u++) xr[u] = xs[u][c];
    const size_t nbase = (size_t)(b * 120 + t) * 25;
    for (int idx = g; idx < 75; idx += 2) {      // (h,v) combos, A reads are s_loads
        int h = idx / 25, v = idx - h * 25;
        const float* Ap = A + (h * 25 + v) * 25;
        float acc = 0.f;
        #pragma unroll
        for (int u = 0; u < 25; u++) acc += Ap[u] * xr[u];
        zt[(nbase + v) * 512 + h * 128 + c] = (bf16)acc;
    }
    for (int v = g; v < 25; v += 2)
        zt[(nbase + v) * 512 + 384 + c] = (bf16)xs[v][c];
}

// ---------------- K2: QKV GEMM 1536 x 48000 x 512 -------------------------
__global__ __launch_bounds__(256) void gemm_qkv(
    const bf16* __restrict__ wcat, const bf16* __restrict__ zt,
    const float* __restrict__ bias,
    bf16* __restrict__ qg, bf16* __restrict__ kg, bf16* __restrict__ vtg)
{
    __shared__ __align__(16) bf16 As[128 * 32];
    __shared__ __align__(16) bf16 Bs[128 * 32];
    const int tid = threadIdx.x, lane = tid & 63, wv = tid >> 6;
    const int wrow = wv >> 1, wcol = wv & 1;
    const int bid = blockIdx.x;
    const int mt = bid % 12, nt = bid / 12;
    const int colb = lane & 15, rg = lane >> 4;

    f32x4 zz = {0.f, 0.f, 0.f, 0.f};
    f32x4 acc[4][4];
    #pragma unroll
    for (int i = 0; i < 4; i++)
        #pragma unroll
        for (int j = 0; j < 4; j++) acc[i][j] = zz;

    const char* gA = (const char*)wcat + (size_t)mt * 128 * 1024; // 1024B rows (512 bf16)
    const char* gB = (const char*)zt + (size_t)nt * 128 * 1024;
    const int srow = lane >> 2, skb = (lane & 3) * 16;
    const int aoff0 = (wrow * 64 + colb) * 64 + rg * 16;  // LDS byte offs (64B rows)
    const int boff0 = (wcol * 64 + colb) * 64 + rg * 16;

    for (int kt = 0; kt < 16; kt++) {
        __syncthreads();
        #pragma unroll
        for (int j = 0; j < 2; j++) {
            int ck = wv * 2 + j;
            int row = ck * 16 + srow;
            GLL16(gA + (size_t)row * 1024 + kt * 64 + skb, (char*)As + ck * 1024);
            GLL16(gB + (size_t)row * 1024 + kt * 64 + skb, (char*)Bs + ck * 1024);
        }
        asm volatile("s_waitcnt vmcnt(0)" ::: "memory");
        __syncthreads();
        bf16x8 af[4], bfr[4];
        #pragma unroll
        for (int m = 0; m < 4; m++)
            af[m] = *(const bf16x8*)((const char*)As + aoff0 + m * 1024);
        #pragma unroll
        for (int n = 0; n < 4; n++)
            bfr[n] = *(const bf16x8*)((const char*)Bs + boff0 + n * 1024);
        #pragma unroll
        for (int m = 0; m < 4; m++)
            #pragma unroll
            for (int n = 0; n < 4; n++)
                acc[m][n] = MFMA16(af[m], bfr[n], acc[m][n]);
    }

    // epilogue: +bias, relu, scatter to Q/K/V^T bf16 (q pre-scaled by 1/8)
    const int obase = mt * 128 + wrow * 64;
    const int nbase = nt * 128 + wcol * 64;
    #pragma unroll
    for (int m = 0; m < 4; m++) {
        #pragma unroll
        for (int reg = 0; reg < 4; reg++) {
            int o = obase + m * 16 + rg * 4 + reg;
            float bo = bias[o];
            int which = o >> 9, rem = o & 511;
            int hd = rem >> 6, dd = rem & 63;
            #pragma unroll
            for (int nn = 0; nn < 4; nn++) {
                int n = nbase + nn * 16 + colb;
                float val = fmaxf(acc[m][nn][reg] + bo, 0.f);
                int b = n / 3000;
                int r2 = n - b * 3000;
                int t = r2 / 25;
                int v = r2 - t * 25;
                int bh = (b * 25 + v) * 8 + hd;
                if (which == 0)
                    qg[((size_t)bh * 120 + t) * 64 + dd] = (bf16)(val * 0.125f);
                else if (which == 1)
                    kg[((size_t)bh * 120 + t) * 64 + dd] = (bf16)val;
                else
                    vtg[((size_t)bh * 64 + dd) * 128 + t] = (bf16)val;
            }
        }
    }
}

// ---------------- K3: causal attention per (b2, head) ---------------------
__global__ __launch_bounds__(256) void attn_k(
    const bf16* __restrict__ qg, const bf16* __restrict__ kg,
    const bf16* __restrict__ vtg, float* __restrict__ attn_out,
    bf16* __restrict__ og)
{
    __shared__ __align__(16) bf16 Ks[128 * 64];   // [t][d] 128B rows, XOR-swizzled
    __shared__ __align__(16) bf16 Vt[64 * 128];   // [d][t] 256B rows, XOR-swizzled
    __shared__ __align__(16) bf16 Ps[128 * 128];  // [tq][tk] 256B rows, XOR-swizzled
    const int tid = threadIdx.x, lane = tid & 63, wv = tid >> 6;
    const int bh = blockIdx.x;
    const int colb = lane & 15, rg = lane >> 4;

    // stage K (960 x 16B) and V^T (1024 x 16B) via global_load_lds with
    // pre-swizzled global source (rule #21: linear dest + inv-swz source)
    const char* ksrc = (const char*)kg + (size_t)bh * 15360;
    const char* vsrc = (const char*)vtg + (size_t)bh * 16384;
    #pragma unroll
    for (int is = 0; is < 4; is++) {
        int cb = is * 256 + wv * 64;             // wave-uniform chunk base
        if (cb < 960) {
            int bb = (cb + lane) * 16;
            int row = bb >> 7;
            int gsrc = (bb & ~127) | ((bb & 127) ^ ((row & 7) << 4));
            GLL16(ksrc + gsrc, (char*)Ks + cb * 16);
        }
        {
            int bb = (cb + lane) * 16;
            int row = bb >> 8;
            int gsrc = (bb & ~255) | ((bb & 255) ^ ((row & 7) << 4));
            GLL16(vsrc + gsrc, (char*)Vt + cb * 16);
        }
    }
    // Q fragments straight to registers (rows of this wave only)
    const char* qsrc = (const char*)qg + (size_t)bh * 15360;
    bf16x8 qf[2][2];
    #pragma unroll
    for (int kk = 0; kk < 2; kk++)
        #pragma unroll
        for (int m = 0; m < 2; m++) {
            int row = wv * 32 + m * 16 + colb;
            qf[kk][m] = *(const bf16x8*)(qsrc + (size_t)row * 128 + rg * 16 + kk * 64);
        }
    asm volatile("s_waitcnt vmcnt(0)" ::: "memory");
    __syncthreads();
    // zero pads: K rows 120..127; Vt logical [d][cols 120..127]
    {
        f32x4 z = {0.f, 0.f, 0.f, 0.f};
        if (tid < 64) {
            int r = 120 + (tid >> 3), off = (tid & 7) * 16;
            *(f32x4*)((char*)Ks + r * 128 + off) = z;
        } else if (tid < 128) {
            int d = tid - 64;
            *(f32x4*)((char*)Vt + d * 256 + (240 ^ ((d & 7) << 4))) = z;
        }
    }
    __syncthreads();

    // S = Q.K^T (q pre-scaled by 1/8 in K2)
    f32x4 accs[2][8];
    #pragma unroll
    for (int m = 0; m < 2; m++)
        #pragma unroll
        for (int ct = 0; ct < 8; ct++) accs[m][ct] = (f32x4){0.f, 0.f, 0.f, 0.f};
    #pragma unroll
    for (int kk = 0; kk < 2; kk++) {
        #pragma unroll
        for (int ct = 0; ct < 8; ct++) {
            int rk = ct * 16 + colb;
            int byo = rk * 128 + ((rg * 16 + kk * 64) ^ ((rk & 7) << 4));
            bf16x8 bk = *(const bf16x8*)((const char*)Ks + byo);
            accs[0][ct] = MFMA16(qf[kk][0], bk, accs[0][ct]);
            accs[1][ct] = MFMA16(qf[kk][1], bk, accs[1][ct]);
        }
    }

    // causal softmax; write attn fp32 to d_out, P bf16 to LDS
    const int rqb = wv * 32;
    float* attn_base = attn_out + (size_t)bh * 120 * 120;
    #pragma unroll
    for (int m = 0; m < 2; m++) {
        #pragma unroll
        for (int reg = 0; reg < 4; reg++) {
            int t_q = rqb + m * 16 + rg * 4 + reg;
            float s[8], mx = -1e30f;
            #pragma unroll
            for (int ct = 0; ct < 8; ct++) {
                int col = ct * 16 + colb;
                bool valid = (col <= t_q) && (col < 120);
                s[ct] = valid ? accs[m][ct][reg] : -1e30f;
                mx = fmaxf(mx, s[ct]);
            }
            #pragma unroll
            for (int d = 1; d < 16; d <<= 1) mx = fmaxf(mx, __shfl_xor(mx, d, 64));
            float p[8], sum = 0.f;
            #pragma unroll
            for (int ct = 0; ct < 8; ct++) {
                p[ct] = (s[ct] > -1e29f) ? __expf(s[ct] - mx) : 0.f;
                sum += p[ct];
            }
            #pragma unroll
            for (int d = 1; d < 16; d <<= 1) sum += __shfl_xor(sum, d, 64);
            float inv = 1.f / sum;
            if (t_q < 120) {
                float* orow = attn_base + (size_t)t_q * 120;
                #pragma unroll
                for (int ct = 0; ct < 8; ct++) {
                    int col = ct * 16 + colb;
                    if (col < 120) orow[col] = p[ct] * inv;
                }
            }
            #pragma unroll
            for (int ct = 0; ct < 8; ct++) {
                int col = ct * 16 + colb;
                int byo = t_q * 256 + ((col * 2) ^ ((t_q & 7) << 4));
                *(bf16*)((char*)Ps + byo) = (bf16)(p[ct] * inv);
            }
        }
    }
    __syncthreads();

    // O = P.V ; causal skip: P rows of wave wv have zero cols >= 32*(wv+1)
    f32x4 acco[2][4];
    #pragma unroll
    for (int m = 0; m < 2; m++)
        #pragma unroll
        for (int dt = 0; dt < 4; dt++) acco[m][dt] = (f32x4){0.f, 0.f, 0.f, 0.f};
    for (int kk = 0; kk <= wv; kk++) {
        bf16x8 ap[2];
        #pragma unroll
        for (int m = 0; m < 2; m++) {
            int row = rqb + m * 16 + colb;
            int byo = row * 256 + ((rg * 16 + kk * 64) ^ ((row & 7) << 4));
            ap[m] = *(const bf16x8*)((const char*)Ps + byo);
        }
        #pragma unroll
        for (int dt = 0; dt < 4; dt++) {
            int rd = dt * 16 + colb;
            int byo = rd * 256 + ((rg * 16 + kk * 64) ^ ((rd & 7) << 4));
            bf16x8 bv = *(const bf16x8*)((const char*)Vt + byo);
            acco[0][dt] = MFMA16(ap[0], bv, acco[0][dt]);
            acco[1][dt] = MFMA16(ap[1], bv, acco[1][dt]);
        }
    }
    const int b2 = bh >> 3, h = bh & 7;
    #pragma unroll
    for (int m = 0; m < 2; m++)
        #pragma unroll
        for (int dt = 0; dt < 4; dt++)
            #pragma unroll
            for (int reg = 0; reg < 4; reg++) {
                int t = rqb + m * 16 + rg * 4 + reg;
                if (t < 120) {
                    int dfull = h * 64 + dt * 16 + colb;
                    og[((size_t)b2 * 120 + t) * 512 + dfull] = (bf16)acco[m][dt][reg];
                }
            }
}

// ---------------- K4: out = o . Wout^T + out_b  (48000 x 128 x 512) -------
__global__ __launch_bounds__(256) void gemm_out_k(
    const bf16* __restrict__ og, const bf16* __restrict__ wout,
    const float* __restrict__ outb, float* __restrict__ out)
{
    __shared__ __align__(16) bf16 As[128 * 32];
    __shared__ __align__(16) bf16 Bs[128 * 32];
    const int tid = threadIdx.x, lane = tid & 63, wv = tid >> 6;
    const int wrow = wv >> 1, wcol = wv & 1;
    const int nt = blockIdx.x;
    const int colb = lane & 15, rg = lane >> 4;

    f32x4 zz = {0.f, 0.f, 0.f, 0.f};
    f32x4 acc[4][4];
    #pragma unroll
    for (int i = 0; i < 4; i++)
        #pragma unroll
        for (int j = 0; j < 4; j++) acc[i][j] = zz;

    const char* gA = (const char*)og + (size_t)nt * 128 * 1024;
    const char* gB = (const char*)wout;
    const int srow = lane >> 2, skb = (lane & 3) * 16;
    const int aoff0 = (wrow * 64 + colb) * 64 + rg * 16;
    const int boff0 = (wcol * 64 + colb) * 64 + rg * 16;

    for (int kt = 0; kt < 16; kt++) {
        __syncthreads();
        #pragma unroll
        for (int j = 0; j < 2; j++) {
            int ck = wv * 2 + j;
            int row = ck * 16 + srow;
            GLL16(gA + (size_t)row * 1024 + kt * 64 + skb, (char*)As + ck * 1024);
            GLL16(gB + (size_t)row * 1024 + kt * 64 + skb, (char*)Bs + ck * 1024);
        }
        asm volatile("s_waitcnt vmcnt(0)" ::: "memory");
        __syncthreads();
        bf16x8 af[4], bfr[4];
        #pragma unroll
        for (int m = 0; m < 4; m++)
            af[m] = *(const bf16x8*)((const char*)As + aoff0 + m * 1024);
        #pragma unroll
        for (int n = 0; n < 4; n++)
            bfr[n] = *(const bf16x8*)((const char*)Bs + boff0 + n * 1024);
        #pragma unroll
        for (int m = 0; m < 4; m++)
            #pragma unroll
            for (int n = 0; n < 4; n++)
                acc[m][n] = MFMA16(af[m], bfr[n], acc[m][n]);
    }

    const int rbase = nt * 128 + wrow * 64;
    #pragma unroll
    for (int m = 0; m < 4; m++)
        #pragma unroll
        for (int reg = 0; reg < 4; reg++) {
            int r = rbase + m * 16 + rg * 4 + reg;
            #pragma unroll
            for (int nn = 0; nn < 4; nn++) {
                int c = wcol * 64 + nn * 16 + colb;
                out[(size_t)r * 128 + c] = acc[m][nn][reg] + outb[c];
            }
        }
}

// ---------------- launch ---------------------------------------------------
extern "C" void kernel_launch(void* const* d_in, const int* in_sizes, int n_in,
                              void* d_out, int out_size, void* d_ws, size_t ws_size,
                              hipStream_t stream)
{
    (void)in_sizes; (void)n_in; (void)out_size; (void)ws_size;
    const float* x      = (const float*)d_in[0];
    const float* A      = (const float*)d_in[1];
    const float* conv_w = (const float*)d_in[2];
    const float* conv_b = (const float*)d_in[3];
    const float* bn_g   = (const float*)d_in[4];
    const float* bn_b   = (const float*)d_in[5];
    const float* bn_m   = (const float*)d_in[6];
    const float* bn_v   = (const float*)d_in[7];
    const float* dw     = (const float*)d_in[8];
    const float* db     = (const float*)d_in[9];
    const float* dg     = (const float*)d_in[10];
    const float* dbb    = (const float*)d_in[11];
    const float* dm     = (const float*)d_in[12];
    const float* dvv    = (const float*)d_in[13];
    const float* out_w  = (const float*)d_in[14];
    const float* out_b  = (const float*)d_in[15];

    char* ws = (char*)d_ws;
    const size_t OFF_WCAT = 0;                       // 1536*512*2   = 1,572,864
    const size_t OFF_WOUT = 1572864;                 // 128*512*2    =   131,072
    const size_t OFF_BIAS = 1703936;                 // 1536*4       =     6,144
    const size_t OFF_ZT   = 1710080;                 // 48000*512*2  = 49,152,000
    const size_t OFF_Q    = 50862080;                // 3200*120*64*2= 49,152,000
    const size_t OFF_K    = 100014080;               // 49,152,000
    const size_t OFF_VT   = 149166080;               // 3200*64*128*2= 52,428,800
    const size_t OFF_O    = OFF_ZT;                  // reuse Zt region after K2

    bf16*  wcat = (bf16*)(ws + OFF_WCAT);
    bf16*  wout = (bf16*)(ws + OFF_WOUT);
    float* bias = (float*)(ws + OFF_BIAS);
    bf16*  zt   = (bf16*)(ws + OFF_ZT);
    bf16*  qg   = (bf16*)(ws + OFF_Q);
    bf16*  kg   = (bf16*)(ws + OFF_K);
    bf16*  vtg  = (bf16*)(ws + OFF_VT);
    bf16*  og   = (bf16*)(ws + OFF_O);
    float* outp = (float*)d_out;
    float* attn = outp + 6144000;                    // out (400,120,128) first

    build_weights<<<3334, 256, 0, stream>>>(conv_w, conv_b, bn_g, bn_b, bn_m, bn_v,
                                            dw, db, dg, dbb, dm, dvv, out_w,
                                            wcat, wout, bias);
    transform<<<1920, 256, 0, stream>>>(x, A, zt);
    gemm_qkv<<<4500, 256, 0, stream>>>(wcat, zt, bias, qg, kg, vtg);
    attn_k<<<3200, 256, 0, stream>>>(qg, kg, vtg, attn, og);
    gemm_out_k<<<375, 256, 0, stream>>>(og, wout, out_b, outp);
}

// Round 2
// 311.760 us; speedup vs baseline: 1.4814x; 1.4814x over previous
//
#include <hip/hip_runtime.h>

// ---------------------------------------------------------------------------
// Attention_28561532519042: GCN-projection + BN + ReLU + causal time-attention
// B2=400 (=16 batch x 25 joints), T=120, C=128, QKV_C=1536, HEADS=8, DH=64
// Pipeline:
//   K1b build_weights : fold BN scales into Wcat[1536x512] bf16, Wout bf16, bias
//   K1  transform     : Zt[48000x512] bf16, rows n=(b*25+v)*120+t
//   K2  gemm_qkv      : QKV = relu(Wcat.Zt + bias); Q/K via LDS-transpose
//                       epilogue (coalesced 16B stores), V^T direct (t-contig)
//   K3  attn_k        : per (b2,h): S=QK^T/8 (causal) -> softmax -> attn (fp32
//                       to d_out) -> O = P.V -> o_ws bf16
//   K4  gemm_out_k    : out = o_ws . Wout^T + out_b  (fp32 to d_out)
// ---------------------------------------------------------------------------

typedef __bf16 bf16;
typedef __bf16 bf16x8 __attribute__((ext_vector_type(8)));
typedef __bf16 bf16x4 __attribute__((ext_vector_type(4)));
typedef float  f32x4  __attribute__((ext_vector_type(4)));
typedef __attribute__((address_space(1))) const void* gptr1;
typedef __attribute__((address_space(3))) void*       lptr3;

#define GLL16(g, l) __builtin_amdgcn_global_load_lds((gptr1)(g), (lptr3)(l), 16, 0, 0)
#define MFMA16(a, b, c) __builtin_amdgcn_mfma_f32_16x16x32_bf16(a, b, c, 0, 0, 0)

// ---------------- K1b: fold BN into weights -------------------------------
__global__ __launch_bounds__(256) void build_weights(
    const float* __restrict__ conv_w, const float* __restrict__ conv_b,
    const float* __restrict__ g1, const float* __restrict__ be1,
    const float* __restrict__ mu1, const float* __restrict__ va1,
    const float* __restrict__ down_w, const float* __restrict__ down_b,
    const float* __restrict__ g2, const float* __restrict__ be2,
    const float* __restrict__ mu2, const float* __restrict__ va2,
    const float* __restrict__ out_w,
    bf16* __restrict__ wcat, bf16* __restrict__ wout, float* __restrict__ bias)
{
    int idx = blockIdx.x * 256 + threadIdx.x;
    if (idx < 1536 * 512) {
        int o = idx >> 9, k = idx & 511;
        float s, w;
        if (k < 384) {
            int h = k >> 7, c = k & 127;
            s = g1[o] * rsqrtf(va1[o] + 1e-5f);
            w = conv_w[(h * 1536 + o) * 128 + c];
        } else {
            s = g2[o] * rsqrtf(va2[o] + 1e-5f);
            w = down_w[o * 128 + (k - 384)];
        }
        wcat[idx] = (bf16)(w * s);
    }
    int i2 = idx - 1536 * 512;
    if (i2 >= 0 && i2 < 128 * 512) wout[i2] = (bf16)out_w[i2];
    int i3 = idx - (1536 * 512 + 128 * 512);
    if (i3 >= 0 && i3 < 1536) {
        int o = i3;
        float s1 = g1[o] * rsqrtf(va1[o] + 1e-5f);
        float s2 = g2[o] * rsqrtf(va2[o] + 1e-5f);
        float cb = conv_b[o] + conv_b[1536 + o] + conv_b[2 * 1536 + o];
        bias[o] = cb * s1 + be1[o] - mu1[o] * s1
                + down_b[o] * s2 + be2[o] - mu2[o] * s2;
    }
}

// ---------------- K1: build Zt[48000][512], n = (b*25+v)*120+t ------------
__global__ __launch_bounds__(256) void transform(
    const float* __restrict__ x, const float* __restrict__ A,
    bf16* __restrict__ zt)
{
    __shared__ float xs[25][128];
    const int tid = threadIdx.x;
    const int bt = blockIdx.x;
    const int b = bt / 120, t = bt - b * 120;
    for (int i = tid; i < 25 * 128; i += 256) {
        int u = i >> 7, c = i & 127;
        xs[u][c] = x[((size_t)(b * 25 + u) * 120 + t) * 128 + c];
    }
    __syncthreads();
    const int c = tid & 127, g = tid >> 7;   // g in {0,1}, wave-uniform
    float xr[25];
    #pragma unroll
    for (int u = 0; u < 25; u++) xr[u] = xs[u][c];
    for (int idx = g; idx < 75; idx += 2) {      // (h,v) combos
        int h = idx / 25, v = idx - h * 25;
        const float* Ap = A + (h * 25 + v) * 25;
        float acc = 0.f;
        #pragma unroll
        for (int u = 0; u < 25; u++) acc += Ap[u] * xr[u];
        zt[((size_t)(b * 25 + v) * 120 + t) * 512 + h * 128 + c] = (bf16)acc;
    }
    for (int v = g; v < 25; v += 2)
        zt[((size_t)(b * 25 + v) * 120 + t) * 512 + 384 + c] = (bf16)xs[v][c];
}

// ---------------- K2: QKV GEMM 1536 x 48000 x 512 -------------------------
// Layouts produced: qg[bh][t][64] (pre-scaled 1/8), kg[bh][t][64],
//                   vtg[bh][dd][128] (cols 120..127 unwritten; zeroed in K3)
__global__ __launch_bounds__(256) void gemm_qkv(
    const bf16* __restrict__ wcat, const bf16* __restrict__ zt,
    const float* __restrict__ bias,
    bf16* __restrict__ qg, bf16* __restrict__ kg, bf16* __restrict__ vtg)
{
    __shared__ __align__(16) char smem[32768];   // 16KB staging / 32KB epi tile
    bf16* AsB = (bf16*)smem;
    bf16* BsB = (bf16*)(smem + 8192);
    const int tid = threadIdx.x, lane = tid & 63, wv = tid >> 6;
    const int wrow = wv >> 1, wcol = wv & 1;
    // bijective XCD swizzle: same-nt blocks land on one XCD (m204)
    const int NB = 4500, q8 = NB >> 3, r8 = NB & 7;   // 562, 4
    const int xcd = blockIdx.x & 7, sidx = blockIdx.x >> 3;
    const int vid = (xcd < r8 ? xcd * (q8 + 1) : r8 * (q8 + 1) + (xcd - r8) * q8) + sidx;
    const int mt = vid % 12, nt = vid / 12;
    const int colb = lane & 15, rg = lane >> 4;

    f32x4 zz = {0.f, 0.f, 0.f, 0.f};
    f32x4 acc[4][4];
    #pragma unroll
    for (int i = 0; i < 4; i++)
        #pragma unroll
        for (int j = 0; j < 4; j++) acc[i][j] = zz;

    const char* gA = (const char*)wcat + (size_t)mt * 128 * 1024; // 1024B rows
    const char* gB = (const char*)zt + (size_t)nt * 128 * 1024;
    const int srow = lane >> 2, skb = (lane & 3) * 16;
    const int aoff0 = (wrow * 64 + colb) * 64 + rg * 16;  // LDS byte offs (64B rows)
    const int boff0 = (wcol * 64 + colb) * 64 + rg * 16;

    for (int kt = 0; kt < 16; kt++) {
        __syncthreads();
        #pragma unroll
        for (int j = 0; j < 2; j++) {
            int ck = wv * 2 + j;
            int row = ck * 16 + srow;
            GLL16(gA + (size_t)row * 1024 + kt * 64 + skb, (char*)AsB + ck * 1024);
            GLL16(gB + (size_t)row * 1024 + kt * 64 + skb, (char*)BsB + ck * 1024);
        }
        asm volatile("s_waitcnt vmcnt(0)" ::: "memory");
        __syncthreads();
        bf16x8 af[4], bfr[4];
        #pragma unroll
        for (int m = 0; m < 4; m++)
            af[m] = *(const bf16x8*)((const char*)AsB + aoff0 + m * 1024);
        #pragma unroll
        for (int n = 0; n < 4; n++)
            bfr[n] = *(const bf16x8*)((const char*)BsB + boff0 + n * 1024);
        #pragma unroll
        for (int m = 0; m < 4; m++)
            #pragma unroll
            for (int n = 0; n < 4; n++)
                acc[m][n] = MFMA16(af[m], bfr[n], acc[m][n]);
    }

    const int mtb = mt * 128, ntb = nt * 128;
    const int which = mtb >> 9;                  // 0=Q, 1=K, 2=V (block-uniform)

    if (which < 2) {
        // ---- LDS-transpose epilogue: Lt[n'][o'] bf16, XOR-swizzled rows ----
        __syncthreads();                         // all waves done with AsB/BsB
        bf16* Lt = (bf16*)smem;                  // [128][128] -> 256B rows
        const float qs = (which == 0) ? 0.125f : 1.0f;
        #pragma unroll
        for (int m = 0; m < 4; m++) {
            int o0 = wrow * 64 + m * 16 + rg * 4;
            float b0 = bias[mtb + o0 + 0], b1 = bias[mtb + o0 + 1];
            float b2 = bias[mtb + o0 + 2], b3 = bias[mtb + o0 + 3];
            #pragma unroll
            for (int nn = 0; nn < 4; nn++) {
                int n_ = wcol * 64 + nn * 16 + colb;
                bf16x4 pk;
                pk[0] = (bf16)(fmaxf(acc[m][nn][0] + b0, 0.f) * qs);
                pk[1] = (bf16)(fmaxf(acc[m][nn][1] + b1, 0.f) * qs);
                pk[2] = (bf16)(fmaxf(acc[m][nn][2] + b2, 0.f) * qs);
                pk[3] = (bf16)(fmaxf(acc[m][nn][3] + b3, 0.f) * qs);
                *(bf16x4*)((char*)Lt + n_ * 256 + ((o0 * 2) ^ ((n_ & 7) << 4))) = pk;
            }
        }
        __syncthreads();
        bf16* dst = (which == 0) ? qg : kg;
        #pragma unroll
        for (int i = 0; i < 8; i++) {
            int ch = i * 256 + tid;
            int n_ = ch >> 4, c16 = ch & 15;
            int ng = ntb + n_;
            int grp = ng / 120, t = ng - grp * 120;      // grp = b*25+v
            int o = mtb + c16 * 8;
            int hd = (o >> 6) & 7, dd0 = o & 63;
            bf16x8 vv = *(const bf16x8*)((const char*)Lt + n_ * 256 +
                                         ((c16 * 16) ^ ((n_ & 7) << 4)));
            *(bf16x8*)(dst + ((size_t)(grp * 8 + hd) * 120 + t) * 64 + dd0) = vv;
        }
    } else {
        // ---- V^T direct: t contiguous across colb -> 32B lane-runs ---------
        #pragma unroll
        for (int m = 0; m < 4; m++) {
            #pragma unroll
            for (int reg = 0; reg < 4; reg++) {
                int o = mtb + wrow * 64 + m * 16 + rg * 4 + reg;
                float bo = bias[o];
                int hd = (o >> 6) & 7, dd = o & 63;
                #pragma unroll
                for (int nn = 0; nn < 4; nn++) {
                    int n = ntb + wcol * 64 + nn * 16 + colb;
                    int grp = n / 120, t = n - grp * 120;
                    float val = fmaxf(acc[m][nn][reg] + bo, 0.f);
                    vtg[((size_t)(grp * 8 + hd) * 64 + dd) * 128 + t] = (bf16)val;
                }
            }
        }
    }
}

// ---------------- K3: causal attention per (b2, head) ---------------------
__global__ __launch_bounds__(256) void attn_k(
    const bf16* __restrict__ qg, const bf16* __restrict__ kg,
    const bf16* __restrict__ vtg, float* __restrict__ attn_out,
    bf16* __restrict__ og)
{
    __shared__ __align__(16) bf16 Ks[128 * 64];   // [t][d] 128B rows, XOR-swizzled
    __shared__ __align__(16) bf16 Vt[64 * 128];   // [d][t] 256B rows, XOR-swizzled
    __shared__ __align__(16) bf16 Ps[128 * 128];  // [tq][tk] 256B rows, XOR-swizzled
    const int tid = threadIdx.x, lane = tid & 63, wv = tid >> 6;
    const int bh = blockIdx.x;
    const int colb = lane & 15, rg = lane >> 4;

    const char* ksrc = (const char*)kg + (size_t)bh * 15360;
    const char* vsrc = (const char*)vtg + (size_t)bh * 16384;
    #pragma unroll
    for (int is = 0; is < 4; is++) {
        int cb = is * 256 + wv * 64;             // wave-uniform chunk base
        if (cb < 960) {
            int bb = (cb + lane) * 16;
            int row = bb >> 7;
            int gsrc = (bb & ~127) | ((bb & 127) ^ ((row & 7) << 4));
            GLL16(ksrc + gsrc, (char*)Ks + cb * 16);
        }
        {
            int bb = (cb + lane) * 16;
            int row = bb >> 8;
            int gsrc = (bb & ~255) | ((bb & 255) ^ ((row & 7) << 4));
            GLL16(vsrc + gsrc, (char*)Vt + cb * 16);
        }
    }
    const char* qsrc = (const char*)qg + (size_t)bh * 15360;
    bf16x8 qf[2][2];
    #pragma unroll
    for (int kk = 0; kk < 2; kk++)
        #pragma unroll
        for (int m = 0; m < 2; m++) {
            int row = wv * 32 + m * 16 + colb;
            qf[kk][m] = *(const bf16x8*)(qsrc + (size_t)row * 128 + rg * 16 + kk * 64);
        }
    asm volatile("s_waitcnt vmcnt(0)" ::: "memory");
    __syncthreads();
    {
        f32x4 z = {0.f, 0.f, 0.f, 0.f};
        if (tid < 64) {
            int r = 120 + (tid >> 3), off = (tid & 7) * 16;
            *(f32x4*)((char*)Ks + r * 128 + off) = z;
        } else if (tid < 128) {
            int d = tid - 64;
            *(f32x4*)((char*)Vt + d * 256 + (240 ^ ((d & 7) << 4))) = z;
        }
    }
    __syncthreads();

    // S = Q.K^T (q pre-scaled by 1/8 in K2)
    f32x4 accs[2][8];
    #pragma unroll
    for (int m = 0; m < 2; m++)
        #pragma unroll
        for (int ct = 0; ct < 8; ct++) accs[m][ct] = (f32x4){0.f, 0.f, 0.f, 0.f};
    #pragma unroll
    for (int kk = 0; kk < 2; kk++) {
        #pragma unroll
        for (int ct = 0; ct < 8; ct++) {
            int rk = ct * 16 + colb;
            int byo = rk * 128 + ((rg * 16 + kk * 64) ^ ((rk & 7) << 4));
            bf16x8 bk = *(const bf16x8*)((const char*)Ks + byo);
            accs[0][ct] = MFMA16(qf[kk][0], bk, accs[0][ct]);
            accs[1][ct] = MFMA16(qf[kk][1], bk, accs[1][ct]);
        }
    }

    // causal softmax; write attn fp32 to d_out, P bf16 to LDS
    const int rqb = wv * 32;
    float* attn_base = attn_out + (size_t)bh * 120 * 120;
    #pragma unroll
    for (int m = 0; m < 2; m++) {
        #pragma unroll
        for (int reg = 0; reg < 4; reg++) {
            int t_q = rqb + m * 16 + rg * 4 + reg;
            float s[8], mx = -1e30f;
            #pragma unroll
            for (int ct = 0; ct < 8; ct++) {
                int col = ct * 16 + colb;
                bool valid = (col <= t_q) && (col < 120);
                s[ct] = valid ? accs[m][ct][reg] : -1e30f;
                mx = fmaxf(mx, s[ct]);
            }
            #pragma unroll
            for (int d = 1; d < 16; d <<= 1) mx = fmaxf(mx, __shfl_xor(mx, d, 64));
            float p[8], sum = 0.f;
            #pragma unroll
            for (int ct = 0; ct < 8; ct++) {
                p[ct] = (s[ct] > -1e29f) ? __expf(s[ct] - mx) : 0.f;
                sum += p[ct];
            }
            #pragma unroll
            for (int d = 1; d < 16; d <<= 1) sum += __shfl_xor(sum, d, 64);
            float inv = 1.f / sum;
            if (t_q < 120) {
                float* orow = attn_base + (size_t)t_q * 120;
                #pragma unroll
                for (int ct = 0; ct < 8; ct++) {
                    int col = ct * 16 + colb;
                    if (col < 120) orow[col] = p[ct] * inv;
                }
            }
            #pragma unroll
            for (int ct = 0; ct < 8; ct++) {
                int col = ct * 16 + colb;
                int byo = t_q * 256 + ((col * 2) ^ ((t_q & 7) << 4));
                *(bf16*)((char*)Ps + byo) = (bf16)(p[ct] * inv);
            }
        }
    }
    __syncthreads();

    // O = P.V ; causal skip: P rows of wave wv have zero cols >= 32*(wv+1)
    f32x4 acco[2][4];
    #pragma unroll
    for (int m = 0; m < 2; m++)
        #pragma unroll
        for (int dt = 0; dt < 4; dt++) acco[m][dt] = (f32x4){0.f, 0.f, 0.f, 0.f};
    for (int kk = 0; kk <= wv; kk++) {
        bf16x8 ap[2];
        #pragma unroll
        for (int m = 0; m < 2; m++) {
            int row = rqb + m * 16 + colb;
            int byo = row * 256 + ((rg * 16 + kk * 64) ^ ((row & 7) << 4));
            ap[m] = *(const bf16x8*)((const char*)Ps + byo);
        }
        #pragma unroll
        for (int dt = 0; dt < 4; dt++) {
            int rd = dt * 16 + colb;
            int byo = rd * 256 + ((rg * 16 + kk * 64) ^ ((rd & 7) << 4));
            bf16x8 bv = *(const bf16x8*)((const char*)Vt + byo);
            acco[0][dt] = MFMA16(ap[0], bv, acco[0][dt]);
            acco[1][dt] = MFMA16(ap[1], bv, acco[1][dt]);
        }
    }
    const int b2 = bh >> 3, h = bh & 7;
    #pragma unroll
    for (int m = 0; m < 2; m++)
        #pragma unroll
        for (int dt = 0; dt < 4; dt++)
            #pragma unroll
            for (int reg = 0; reg < 4; reg++) {
                int t = rqb + m * 16 + rg * 4 + reg;
                if (t < 120) {
                    int dfull = h * 64 + dt * 16 + colb;
                    og[((size_t)b2 * 120 + t) * 512 + dfull] = (bf16)acco[m][dt][reg];
                }
            }
}

// ---------------- K4: out = o . Wout^T + out_b  (48000 x 128 x 512) -------
__global__ __launch_bounds__(256) void gemm_out_k(
    const bf16* __restrict__ og, const bf16* __restrict__ wout,
    const float* __restrict__ outb, float* __restrict__ out)
{
    __shared__ __align__(16) bf16 As[128 * 32];
    __shared__ __align__(16) bf16 Bs[128 * 32];
    const int tid = threadIdx.x, lane = tid & 63, wv = tid >> 6;
    const int wrow = wv >> 1, wcol = wv & 1;
    const int nt = blockIdx.x;
    const int colb = lane & 15, rg = lane >> 4;

    f32x4 zz = {0.f, 0.f, 0.f, 0.f};
    f32x4 acc[4][4];
    #pragma unroll
    for (int i = 0; i < 4; i++)
        #pragma unroll
        for (int j = 0; j < 4; j++) acc[i][j] = zz;

    const char* gA = (const char*)og + (size_t)nt * 128 * 1024;
    const char* gB = (const char*)wout;
    const int srow = lane >> 2, skb = (lane & 3) * 16;
    const int aoff0 = (wrow * 64 + colb) * 64 + rg * 16;
    const int boff0 = (wcol * 64 + colb) * 64 + rg * 16;

    for (int kt = 0; kt < 16; kt++) {
        __syncthreads();
        #pragma unroll
        for (int j = 0; j < 2; j++) {
            int ck = wv * 2 + j;
            int row = ck * 16 + srow;
            GLL16(gA + (size_t)row * 1024 + kt * 64 + skb, (char*)As + ck * 1024);
            GLL16(gB + (size_t)row * 1024 + kt * 64 + skb, (char*)Bs + ck * 1024);
        }
        asm volatile("s_waitcnt vmcnt(0)" ::: "memory");
        __syncthreads();
        bf16x8 af[4], bfr[4];
        #pragma unroll
        for (int m = 0; m < 4; m++)
            af[m] = *(const bf16x8*)((const char*)As + aoff0 + m * 1024);
        #pragma unroll
        for (int n = 0; n < 4; n++)
            bfr[n] = *(const bf16x8*)((const char*)Bs + boff0 + n * 1024);
        #pragma unroll
        for (int m = 0; m < 4; m++)
            #pragma unroll
            for (int n = 0; n < 4; n++)
                acc[m][n] = MFMA16(af[m], bfr[n], acc[m][n]);
    }

    const int rbase = nt * 128 + wrow * 64;
    #pragma unroll
    for (int m = 0; m < 4; m++)
        #pragma unroll
        for (int reg = 0; reg < 4; reg++) {
            int r = rbase + m * 16 + rg * 4 + reg;
            #pragma unroll
            for (int nn = 0; nn < 4; nn++) {
                int c = wcol * 64 + nn * 16 + colb;
                out[(size_t)r * 128 + c] = acc[m][nn][reg] + outb[c];
            }
        }
}

// ---------------- launch ---------------------------------------------------
extern "C" void kernel_launch(void* const* d_in, const int* in_sizes, int n_in,
                              void* d_out, int out_size, void* d_ws, size_t ws_size,
                              hipStream_t stream)
{
    (void)in_sizes; (void)n_in; (void)out_size; (void)ws_size;
    const float* x      = (const float*)d_in[0];
    const float* A      = (const float*)d_in[1];
    const float* conv_w = (const float*)d_in[2];
    const float* conv_b = (const float*)d_in[3];
    const float* bn_g   = (const float*)d_in[4];
    const float* bn_b   = (const float*)d_in[5];
    const float* bn_m   = (const float*)d_in[6];
    const float* bn_v   = (const float*)d_in[7];
    const float* dw     = (const float*)d_in[8];
    const float* db     = (const float*)d_in[9];
    const float* dg     = (const float*)d_in[10];
    const float* dbb    = (const float*)d_in[11];
    const float* dm     = (const float*)d_in[12];
    const float* dvv    = (const float*)d_in[13];
    const float* out_w  = (const float*)d_in[14];
    const float* out_b  = (const float*)d_in[15];

    char* ws = (char*)d_ws;
    const size_t OFF_WCAT = 0;                       // 1536*512*2   = 1,572,864
    const size_t OFF_WOUT = 1572864;                 // 128*512*2    =   131,072
    const size_t OFF_BIAS = 1703936;                 // 1536*4       =     6,144
    const size_t OFF_ZT   = 1710080;                 // 48000*512*2  = 49,152,000
    const size_t OFF_Q    = 50862080;                // 3200*120*64*2= 49,152,000
    const size_t OFF_K    = 100014080;               // 49,152,000
    const size_t OFF_VT   = 149166080;               // 3200*64*128*2= 52,428,800
    const size_t OFF_O    = OFF_ZT;                  // reuse Zt region after K2

    bf16*  wcat = (bf16*)(ws + OFF_WCAT);
    bf16*  wout = (bf16*)(ws + OFF_WOUT);
    float* bias = (float*)(ws + OFF_BIAS);
    bf16*  zt   = (bf16*)(ws + OFF_ZT);
    bf16*  qg   = (bf16*)(ws + OFF_Q);
    bf16*  kg   = (bf16*)(ws + OFF_K);
    bf16*  vtg  = (bf16*)(ws + OFF_VT);
    bf16*  og   = (bf16*)(ws + OFF_O);
    float* outp = (float*)d_out;
    float* attn = outp + 6144000;                    // out (400,120,128) first

    build_weights<<<3334, 256, 0, stream>>>(conv_w, conv_b, bn_g, bn_b, bn_m, bn_v,
                                            dw, db, dg, dbb, dm, dvv, out_w,
                                            wcat, wout, bias);
    transform<<<1920, 256, 0, stream>>>(x, A, zt);
    gemm_qkv<<<4500, 256, 0, stream>>>(wcat, zt, bias, qg, kg, vtg);
    attn_k<<<3200, 256, 0, stream>>>(qg, kg, vtg, attn, og);
    gemm_out_k<<<375, 256, 0, stream>>>(og, wout, out_b, outp);
}

// Round 3
// 284.173 us; speedup vs baseline: 1.6252x; 1.0971x over previous
//
#include <hip/hip_runtime.h>

// ---------------------------------------------------------------------------
// Attention_28561532519042: GCN-projection + BN + ReLU + causal time-attention
// B2=400 (=16 batch x 25 joints), T=120, C=128, QKV_C=1536, HEADS=8, DH=64
// Pipeline:
//   K1b build_weights : fold BN scales into Wcat[1536x512] bf16, Wout bf16, bias
//   K1  transform     : Zt[48000x512] bf16, rows n=(b*25+v)*120+t
//   K2  gemm_qkv      : QKV = relu(Wcat.Zt + bias); 3-buf 2-deep pipelined
//                       K-loop (counted vmcnt(4), raw s_barrier); Q/K via
//                       LDS-transpose epilogue, V^T direct (t-contig)
//   K3  attn_k        : per (b2,h): S=QK^T/8 (causal) -> softmax -> attn (fp32
//                       to d_out) -> O = P.V -> o_ws bf16  (Ps aliases Ks)
//   K4  gemm_out_k    : out = o_ws . Wout^T + out_b, same pipelined loop
// ---------------------------------------------------------------------------

typedef __bf16 bf16;
typedef __bf16 bf16x8 __attribute__((ext_vector_type(8)));
typedef __bf16 bf16x4 __attribute__((ext_vector_type(4)));
typedef float  f32x4  __attribute__((ext_vector_type(4)));
typedef __attribute__((address_space(1))) const void* gptr1;
typedef __attribute__((address_space(3))) void*       lptr3;

#define GLL16(g, l) __builtin_amdgcn_global_load_lds((gptr1)(g), (lptr3)(l), 16, 0, 0)
#define MFMA16(a, b, c) __builtin_amdgcn_mfma_f32_16x16x32_bf16(a, b, c, 0, 0, 0)

// ---------------- K1b: fold BN into weights -------------------------------
__global__ __launch_bounds__(256) void build_weights(
    const float* __restrict__ conv_w, const float* __restrict__ conv_b,
    const float* __restrict__ g1, const float* __restrict__ be1,
    const float* __restrict__ mu1, const float* __restrict__ va1,
    const float* __restrict__ down_w, const float* __restrict__ down_b,
    const float* __restrict__ g2, const float* __restrict__ be2,
    const float* __restrict__ mu2, const float* __restrict__ va2,
    const float* __restrict__ out_w,
    bf16* __restrict__ wcat, bf16* __restrict__ wout, float* __restrict__ bias)
{
    int idx = blockIdx.x * 256 + threadIdx.x;
    if (idx < 1536 * 512) {
        int o = idx >> 9, k = idx & 511;
        float s, w;
        if (k < 384) {
            int h = k >> 7, c = k & 127;
            s = g1[o] * rsqrtf(va1[o] + 1e-5f);
            w = conv_w[(h * 1536 + o) * 128 + c];
        } else {
            s = g2[o] * rsqrtf(va2[o] + 1e-5f);
            w = down_w[o * 128 + (k - 384)];
        }
        wcat[idx] = (bf16)(w * s);
    }
    int i2 = idx - 1536 * 512;
    if (i2 >= 0 && i2 < 128 * 512) wout[i2] = (bf16)out_w[i2];
    int i3 = idx - (1536 * 512 + 128 * 512);
    if (i3 >= 0 && i3 < 1536) {
        int o = i3;
        float s1 = g1[o] * rsqrtf(va1[o] + 1e-5f);
        float s2 = g2[o] * rsqrtf(va2[o] + 1e-5f);
        float cb = conv_b[o] + conv_b[1536 + o] + conv_b[2 * 1536 + o];
        bias[o] = cb * s1 + be1[o] - mu1[o] * s1
                + down_b[o] * s2 + be2[o] - mu2[o] * s2;
    }
}

// ---------------- K1: build Zt[48000][512], n = (b*25+v)*120+t ------------
__global__ __launch_bounds__(256) void transform(
    const float* __restrict__ x, const float* __restrict__ A,
    bf16* __restrict__ zt)
{
    __shared__ float xs[25][128];
    const int tid = threadIdx.x;
    const int bt = blockIdx.x;
    const int b = bt / 120, t = bt - b * 120;
    for (int i = tid; i < 25 * 128; i += 256) {
        int u = i >> 7, c = i & 127;
        xs[u][c] = x[((size_t)(b * 25 + u) * 120 + t) * 128 + c];
    }
    __syncthreads();
    const int c = tid & 127, g = tid >> 7;   // g in {0,1}, wave-uniform
    float xr[25];
    #pragma unroll
    for (int u = 0; u < 25; u++) xr[u] = xs[u][c];
    for (int idx = g; idx < 75; idx += 2) {      // (h,v) combos
        int h = idx / 25, v = idx - h * 25;
        const float* Ap = A + (h * 25 + v) * 25;
        float acc = 0.f;
        #pragma unroll
        for (int u = 0; u < 25; u++) acc += Ap[u] * xr[u];
        zt[((size_t)(b * 25 + v) * 120 + t) * 512 + h * 128 + c] = (bf16)acc;
    }
    for (int v = g; v < 25; v += 2)
        zt[((size_t)(b * 25 + v) * 120 + t) * 512 + 384 + c] = (bf16)xs[v][c];
}

// ---------------- K2: QKV GEMM 1536 x 48000 x 512 -------------------------
// 3-buffer 2-deep pipelined K-loop; counted vmcnt(4); raw s_barrier.
// Layouts produced: qg[bh][t][64] (pre-scaled 1/8), kg[bh][t][64],
//                   vtg[bh][dd][128] (cols 120..127 unwritten; zeroed in K3)
__global__ __launch_bounds__(256) void gemm_qkv(
    const bf16* __restrict__ wcat, const bf16* __restrict__ zt,
    const float* __restrict__ bias,
    bf16* __restrict__ qg, bf16* __restrict__ kg, bf16* __restrict__ vtg)
{
    __shared__ __align__(16) char smem[49152];   // 3 x (A 8KB + B 8KB); Lt epi 32KB
    const int tid = threadIdx.x, lane = tid & 63, wv = tid >> 6;
    const int wrow = wv >> 1, wcol = wv & 1;
    // bijective XCD swizzle: same-nt blocks land on one XCD (m204)
    const int NB = 4500, q8 = NB >> 3, r8 = NB & 7;   // 562, 4
    const int xcd = blockIdx.x & 7, sidx = blockIdx.x >> 3;
    const int vid = (xcd < r8 ? xcd * (q8 + 1) : r8 * (q8 + 1) + (xcd - r8) * q8) + sidx;
    const int mt = vid % 12, nt = vid / 12;
    const int colb = lane & 15, rg = lane >> 4;

    f32x4 zz = {0.f, 0.f, 0.f, 0.f};
    f32x4 acc[4][4];
    #pragma unroll
    for (int i = 0; i < 4; i++)
        #pragma unroll
        for (int j = 0; j < 4; j++) acc[i][j] = zz;

    const char* gA = (const char*)wcat + (size_t)mt * 128 * 1024; // 1024B rows
    const char* gB = (const char*)zt + (size_t)nt * 128 * 1024;
    const int srow = lane >> 2, skb = (lane & 3) * 16;
    const int aoff0 = (wrow * 64 + colb) * 64 + rg * 16;  // LDS byte offs (64B rows)
    const int boff0 = (wcol * 64 + colb) * 64 + rg * 16;

    #define STAGE_QKV(kt, b) do {                                              \
        char* As_ = smem + (b) * 16384; char* Bs_ = As_ + 8192;                \
        _Pragma("unroll")                                                      \
        for (int j = 0; j < 2; j++) {                                          \
            int ck = wv * 2 + j;  int row = ck * 16 + srow;                    \
            GLL16(gA + (size_t)row * 1024 + (kt) * 64 + skb, As_ + ck * 1024); \
            GLL16(gB + (size_t)row * 1024 + (kt) * 64 + skb, Bs_ + ck * 1024); \
        } } while (0)

    STAGE_QKV(0, 0);
    STAGE_QKV(1, 1);
    asm volatile("s_waitcnt vmcnt(4)" ::: "memory");   // tile 0 landed
    __builtin_amdgcn_s_barrier();
    for (int kt = 0; kt < 16; kt++) {
        const char* As = smem + (kt % 3) * 16384;
        const char* Bs = As + 8192;
        bf16x8 af[4], bfr[4];
        #pragma unroll
        for (int m = 0; m < 4; m++)
            af[m] = *(const bf16x8*)(As + aoff0 + m * 1024);
        #pragma unroll
        for (int n = 0; n < 4; n++)
            bfr[n] = *(const bf16x8*)(Bs + boff0 + n * 1024);
        int kn = kt + 2;
        STAGE_QKV(kn < 16 ? kn : 15, kn % 3);          // dummy keeps counts fixed
        __builtin_amdgcn_s_setprio(1);
        #pragma unroll
        for (int m = 0; m < 4; m++)
            #pragma unroll
            for (int n = 0; n < 4; n++)
                acc[m][n] = MFMA16(af[m], bfr[n], acc[m][n]);
        __builtin_amdgcn_s_setprio(0);
        asm volatile("s_waitcnt vmcnt(4)" ::: "memory"); // tile kt+1 landed
        __builtin_amdgcn_s_barrier();
    }
    __builtin_amdgcn_sched_barrier(0);

    const int mtb = mt * 128, ntb = nt * 128;
    const int which = mtb >> 9;                  // 0=Q, 1=K, 2=V (block-uniform)

    if (which < 2) {
        // ---- LDS-transpose epilogue: Lt[n'][o'] bf16, XOR-swizzled rows ----
        // Lt uses smem[0..32KB); in-flight dummy writes target [32KB..48KB).
        bf16* Lt = (bf16*)smem;                  // [128][128] -> 256B rows
        const float qs = (which == 0) ? 0.125f : 1.0f;
        #pragma unroll
        for (int m = 0; m < 4; m++) {
            int o0 = wrow * 64 + m * 16 + rg * 4;
            float b0 = bias[mtb + o0 + 0], b1 = bias[mtb + o0 + 1];
            float b2 = bias[mtb + o0 + 2], b3 = bias[mtb + o0 + 3];
            #pragma unroll
            for (int nn = 0; nn < 4; nn++) {
                int n_ = wcol * 64 + nn * 16 + colb;
                bf16x4 pk;
                pk[0] = (bf16)(fmaxf(acc[m][nn][0] + b0, 0.f) * qs);
                pk[1] = (bf16)(fmaxf(acc[m][nn][1] + b1, 0.f) * qs);
                pk[2] = (bf16)(fmaxf(acc[m][nn][2] + b2, 0.f) * qs);
                pk[3] = (bf16)(fmaxf(acc[m][nn][3] + b3, 0.f) * qs);
                *(bf16x4*)((char*)Lt + n_ * 256 + ((o0 * 2) ^ ((n_ & 7) << 4))) = pk;
            }
        }
        __syncthreads();
        bf16* dst = (which == 0) ? qg : kg;
        #pragma unroll
        for (int i = 0; i < 8; i++) {
            int ch = i * 256 + tid;
            int n_ = ch >> 4, c16 = ch & 15;
            int ng = ntb + n_;
            int grp = ng / 120, t = ng - grp * 120;      // grp = b*25+v
            int o = mtb + c16 * 8;
            int hd = (o >> 6) & 7, dd0 = o & 63;
            bf16x8 vv = *(const bf16x8*)((const char*)Lt + n_ * 256 +
                                         ((c16 * 16) ^ ((n_ & 7) << 4)));
            *(bf16x8*)(dst + ((size_t)(grp * 8 + hd) * 120 + t) * 64 + dd0) = vv;
        }
    } else {
        // ---- V^T direct: t contiguous across colb -> 32B lane-runs ---------
        #pragma unroll
        for (int m = 0; m < 4; m++) {
            #pragma unroll
            for (int reg = 0; reg < 4; reg++) {
                int o = mtb + wrow * 64 + m * 16 + rg * 4 + reg;
                float bo = bias[o];
                int hd = (o >> 6) & 7, dd = o & 63;
                #pragma unroll
                for (int nn = 0; nn < 4; nn++) {
                    int n = ntb + wcol * 64 + nn * 16 + colb;
                    int grp = n / 120, t = n - grp * 120;
                    float val = fmaxf(acc[m][nn][reg] + bo, 0.f);
                    vtg[((size_t)(grp * 8 + hd) * 64 + dd) * 128 + t] = (bf16)val;
                }
            }
        }
    }
    #undef STAGE_QKV
}

// ---------------- K3: causal attention per (b2, head) ---------------------
// LDS 48KB: Vt[16KB] | Ks[16KB] ; Ps[32KB] aliases Ks after QK^T.
__global__ __launch_bounds__(256) void attn_k(
    const bf16* __restrict__ qg, const bf16* __restrict__ kg,
    const bf16* __restrict__ vtg, float* __restrict__ attn_out,
    bf16* __restrict__ og)
{
    __shared__ __align__(16) char sm[49152];
    char* Vt = sm;                // [d][t] 256B rows, XOR-swizzled  (16KB)
    char* Ks = sm + 16384;        // [t][d] 128B rows, XOR-swizzled  (16KB)
    char* Ps = sm + 16384;        // [tq][tk] 256B rows, XOR-swizzled (32KB)
    const int tid = threadIdx.x, lane = tid & 63, wv = tid >> 6;
    const int bh = blockIdx.x;
    const int colb = lane & 15, rg = lane >> 4;

    const char* ksrc = (const char*)kg + (size_t)bh * 15360;
    const char* vsrc = (const char*)vtg + (size_t)bh * 16384;
    #pragma unroll
    for (int is = 0; is < 4; is++) {
        int cb = is * 256 + wv * 64;             // wave-uniform chunk base
        if (cb < 960) {
            int bb = (cb + lane) * 16;
            int row = bb >> 7;
            int gsrc = (bb & ~127) | ((bb & 127) ^ ((row & 7) << 4));
            GLL16(ksrc + gsrc, Ks + cb * 16);
        }
        {
            int bb = (cb + lane) * 16;
            int row = bb >> 8;
            int gsrc = (bb & ~255) | ((bb & 255) ^ ((row & 7) << 4));
            GLL16(vsrc + gsrc, Vt + cb * 16);
        }
    }
    const char* qsrc = (const char*)qg + (size_t)bh * 15360;
    bf16x8 qf[2][2];
    #pragma unroll
    for (int kk = 0; kk < 2; kk++)
        #pragma unroll
        for (int m = 0; m < 2; m++) {
            int row = wv * 32 + m * 16 + colb;
            qf[kk][m] = *(const bf16x8*)(qsrc + (size_t)row * 128 + rg * 16 + kk * 64);
        }
    asm volatile("s_waitcnt vmcnt(0)" ::: "memory");
    __syncthreads();
    {
        f32x4 z = {0.f, 0.f, 0.f, 0.f};
        if (tid < 64) {
            int r = 120 + (tid >> 3), off = (tid & 7) * 16;
            *(f32x4*)(Ks + r * 128 + off) = z;
        } else if (tid < 128) {
            int d = tid - 64;
            *(f32x4*)(Vt + d * 256 + (240 ^ ((d & 7) << 4))) = z;
        }
    }
    __syncthreads();

    // S = Q.K^T (q pre-scaled by 1/8 in K2)
    f32x4 accs[2][8];
    #pragma unroll
    for (int m = 0; m < 2; m++)
        #pragma unroll
        for (int ct = 0; ct < 8; ct++) accs[m][ct] = (f32x4){0.f, 0.f, 0.f, 0.f};
    #pragma unroll
    for (int kk = 0; kk < 2; kk++) {
        #pragma unroll
        for (int ct = 0; ct < 8; ct++) {
            int rk = ct * 16 + colb;
            int byo = rk * 128 + ((rg * 16 + kk * 64) ^ ((rk & 7) << 4));
            bf16x8 bk = *(const bf16x8*)(Ks + byo);
            accs[0][ct] = MFMA16(qf[kk][0], bk, accs[0][ct]);
            accs[1][ct] = MFMA16(qf[kk][1], bk, accs[1][ct]);
        }
    }
    __syncthreads();   // Ks dead; Ps may now overwrite it

    // causal softmax; write attn fp32 to d_out, P bf16 to LDS
    const int rqb = wv * 32;
    float* attn_base = attn_out + (size_t)bh * 120 * 120;
    #pragma unroll
    for (int m = 0; m < 2; m++) {
        #pragma unroll
        for (int reg = 0; reg < 4; reg++) {
            int t_q = rqb + m * 16 + rg * 4 + reg;
            float s[8], mx = -1e30f;
            #pragma unroll
            for (int ct = 0; ct < 8; ct++) {
                int col = ct * 16 + colb;
                bool valid = (col <= t_q) && (col < 120);
                s[ct] = valid ? accs[m][ct][reg] : -1e30f;
                mx = fmaxf(mx, s[ct]);
            }
            #pragma unroll
            for (int d = 1; d < 16; d <<= 1) mx = fmaxf(mx, __shfl_xor(mx, d, 64));
            float p[8], sum = 0.f;
            #pragma unroll
            for (int ct = 0; ct < 8; ct++) {
                p[ct] = (s[ct] > -1e29f) ? __expf(s[ct] - mx) : 0.f;
                sum += p[ct];
            }
            #pragma unroll
            for (int d = 1; d < 16; d <<= 1) sum += __shfl_xor(sum, d, 64);
            float inv = 1.f / sum;
            if (t_q < 120) {
                float* orow = attn_base + (size_t)t_q * 120;
                #pragma unroll
                for (int ct = 0; ct < 8; ct++) {
                    int col = ct * 16 + colb;
                    if (col < 120) orow[col] = p[ct] * inv;
                }
            }
            #pragma unroll
            for (int ct = 0; ct < 8; ct++) {
                int col = ct * 16 + colb;
                int byo = t_q * 256 + ((col * 2) ^ ((t_q & 7) << 4));
                *(bf16*)(Ps + byo) = (bf16)(p[ct] * inv);
            }
        }
    }
    __syncthreads();

    // O = P.V ; causal skip: P rows of wave wv have zero cols >= 32*(wv+1)
    f32x4 acco[2][4];
    #pragma unroll
    for (int m = 0; m < 2; m++)
        #pragma unroll
        for (int dt = 0; dt < 4; dt++) acco[m][dt] = (f32x4){0.f, 0.f, 0.f, 0.f};
    for (int kk = 0; kk <= wv; kk++) {
        bf16x8 ap[2];
        #pragma unroll
        for (int m = 0; m < 2; m++) {
            int row = rqb + m * 16 + colb;
            int byo = row * 256 + ((rg * 16 + kk * 64) ^ ((row & 7) << 4));
            ap[m] = *(const bf16x8*)(Ps + byo);
        }
        #pragma unroll
        for (int dt = 0; dt < 4; dt++) {
            int rd = dt * 16 + colb;
            int byo = rd * 256 + ((rg * 16 + kk * 64) ^ ((rd & 7) << 4));
            bf16x8 bv = *(const bf16x8*)(Vt + byo);
            acco[0][dt] = MFMA16(ap[0], bv, acco[0][dt]);
            acco[1][dt] = MFMA16(ap[1], bv, acco[1][dt]);
        }
    }
    const int b2 = bh >> 3, h = bh & 7;
    #pragma unroll
    for (int m = 0; m < 2; m++)
        #pragma unroll
        for (int dt = 0; dt < 4; dt++)
            #pragma unroll
            for (int reg = 0; reg < 4; reg++) {
                int t = rqb + m * 16 + rg * 4 + reg;
                if (t < 120) {
                    int dfull = h * 64 + dt * 16 + colb;
                    og[((size_t)b2 * 120 + t) * 512 + dfull] = (bf16)acco[m][dt][reg];
                }
            }
}

// ---------------- K4: out = o . Wout^T + out_b  (48000 x 128 x 512) -------
__global__ __launch_bounds__(256) void gemm_out_k(
    const bf16* __restrict__ og, const bf16* __restrict__ wout,
    const float* __restrict__ outb, float* __restrict__ out)
{
    __shared__ __align__(16) char smem[49152];
    const int tid = threadIdx.x, lane = tid & 63, wv = tid >> 6;
    const int wrow = wv >> 1, wcol = wv & 1;
    const int nt = blockIdx.x;
    const int colb = lane & 15, rg = lane >> 4;

    f32x4 zz = {0.f, 0.f, 0.f, 0.f};
    f32x4 acc[4][4];
    #pragma unroll
    for (int i = 0; i < 4; i++)
        #pragma unroll
        for (int j = 0; j < 4; j++) acc[i][j] = zz;

    const char* gA = (const char*)og + (size_t)nt * 128 * 1024;
    const char* gB = (const char*)wout;
    const int srow = lane >> 2, skb = (lane & 3) * 16;
    const int aoff0 = (wrow * 64 + colb) * 64 + rg * 16;
    const int boff0 = (wcol * 64 + colb) * 64 + rg * 16;

    #define STAGE_OUT(kt, b) do {                                              \
        char* As_ = smem + (b) * 16384; char* Bs_ = As_ + 8192;                \
        _Pragma("unroll")                                                      \
        for (int j = 0; j < 2; j++) {                                          \
            int ck = wv * 2 + j;  int row = ck * 16 + srow;                    \
            GLL16(gA + (size_t)row * 1024 + (kt) * 64 + skb, As_ + ck * 1024); \
            GLL16(gB + (size_t)row * 1024 + (kt) * 64 + skb, Bs_ + ck * 1024); \
        } } while (0)

    STAGE_OUT(0, 0);
    STAGE_OUT(1, 1);
    asm volatile("s_waitcnt vmcnt(4)" ::: "memory");
    __builtin_amdgcn_s_barrier();
    for (int kt = 0; kt < 16; kt++) {
        const char* As = smem + (kt % 3) * 16384;
        const char* Bs = As + 8192;
        bf16x8 af[4], bfr[4];
        #pragma unroll
        for (int m = 0; m < 4; m++)
            af[m] = *(const bf16x8*)(As + aoff0 + m * 1024);
        #pragma unroll
        for (int n = 0; n < 4; n++)
            bfr[n] = *(const bf16x8*)(Bs + boff0 + n * 1024);
        int kn = kt + 2;
        STAGE_OUT(kn < 16 ? kn : 15, kn % 3);
        __builtin_amdgcn_s_setprio(1);
        #pragma unroll
        for (int m = 0; m < 4; m++)
            #pragma unroll
            for (int n = 0; n < 4; n++)
                acc[m][n] = MFMA16(af[m], bfr[n], acc[m][n]);
        __builtin_amdgcn_s_setprio(0);
        asm volatile("s_waitcnt vmcnt(4)" ::: "memory");
        __builtin_amdgcn_s_barrier();
    }
    __builtin_amdgcn_sched_barrier(0);

    const int rbase = nt * 128 + wrow * 64;
    #pragma unroll
    for (int m = 0; m < 4; m++)
        #pragma unroll
        for (int reg = 0; reg < 4; reg++) {
            int r = rbase + m * 16 + rg * 4 + reg;
            #pragma unroll
            for (int nn = 0; nn < 4; nn++) {
                int c = wcol * 64 + nn * 16 + colb;
                out[(size_t)r * 128 + c] = acc[m][nn][reg] + outb[c];
            }
        }
    #undef STAGE_OUT
}

// ---------------- launch ---------------------------------------------------
extern "C" void kernel_launch(void* const* d_in, const int* in_sizes, int n_in,
                              void* d_out, int out_size, void* d_ws, size_t ws_size,
                              hipStream_t stream)
{
    (void)in_sizes; (void)n_in; (void)out_size; (void)ws_size;
    const float* x      = (const float*)d_in[0];
    const float* A      = (const float*)d_in[1];
    const float* conv_w = (const float*)d_in[2];
    const float* conv_b = (const float*)d_in[3];
    const float* bn_g   = (const float*)d_in[4];
    const float* bn_b   = (const float*)d_in[5];
    const float* bn_m   = (const float*)d_in[6];
    const float* bn_v   = (const float*)d_in[7];
    const float* dw     = (const float*)d_in[8];
    const float* db     = (const float*)d_in[9];
    const float* dg     = (const float*)d_in[10];
    const float* dbb    = (const float*)d_in[11];
    const float* dm     = (const float*)d_in[12];
    const float* dvv    = (const float*)d_in[13];
    const float* out_w  = (const float*)d_in[14];
    const float* out_b  = (const float*)d_in[15];

    char* ws = (char*)d_ws;
    const size_t OFF_WCAT = 0;                       // 1536*512*2   = 1,572,864
    const size_t OFF_WOUT = 1572864;                 // 128*512*2    =   131,072
    const size_t OFF_BIAS = 1703936;                 // 1536*4       =     6,144
    const size_t OFF_ZT   = 1710080;                 // 48000*512*2  = 49,152,000
    const size_t OFF_Q    = 50862080;                // 3200*120*64*2= 49,152,000
    const size_t OFF_K    = 100014080;               // 49,152,000
    const size_t OFF_VT   = 149166080;               // 3200*64*128*2= 52,428,800
    const size_t OFF_O    = OFF_ZT;                  // reuse Zt region after K2

    bf16*  wcat = (bf16*)(ws + OFF_WCAT);
    bf16*  wout = (bf16*)(ws + OFF_WOUT);
    float* bias = (float*)(ws + OFF_BIAS);
    bf16*  zt   = (bf16*)(ws + OFF_ZT);
    bf16*  qg   = (bf16*)(ws + OFF_Q);
    bf16*  kg   = (bf16*)(ws + OFF_K);
    bf16*  vtg  = (bf16*)(ws + OFF_VT);
    bf16*  og   = (bf16*)(ws + OFF_O);
    float* outp = (float*)d_out;
    float* attn = outp + 6144000;                    // out (400,120,128) first

    build_weights<<<3334, 256, 0, stream>>>(conv_w, conv_b, bn_g, bn_b, bn_m, bn_v,
                                            dw, db, dg, dbb, dm, dvv, out_w,
                                            wcat, wout, bias);
    transform<<<1920, 256, 0, stream>>>(x, A, zt);
    gemm_qkv<<<4500, 256, 0, stream>>>(wcat, zt, bias, qg, kg, vtg);
    attn_k<<<3200, 256, 0, stream>>>(qg, kg, vtg, attn, og);
    gemm_out_k<<<375, 256, 0, stream>>>(og, wout, out_b, outp);
}

// Round 4
// 282.065 us; speedup vs baseline: 1.6374x; 1.0075x over previous
//
#include <hip/hip_runtime.h>

// ---------------------------------------------------------------------------
// Attention_28561532519042: GCN-projection + BN + ReLU + causal time-attention
// B2=400 (=16 batch x 25 joints), T=120, C=128, QKV_C=1536, HEADS=8, DH=64
// Pipeline:
//   K1b build_weights : fold BN scales into Wcat[1536x512] bf16, Wout bf16, bias
//   K1  transform     : Zt[48000x512] bf16, rows n=(b*25+v)*120+t
//   K2  gemm_qkv      : QKV = relu(Wcat.Zt + bias); 3-buf 2-deep pipelined
//                       K-loop (counted vmcnt(4), raw s_barrier); CONFLICT-FREE
//                       slot-swizzled LDS (phys slot s holds logical s^((r>>1)&3));
//                       Q/K via LDS-transpose epilogue, V^T direct (t-contig)
//   K3  attn_k        : per (b2,h): S=QK^T/8 (causal) -> softmax -> attn (fp32
//                       to d_out) -> O = P.V -> o_ws bf16  (Ps aliases Ks)
//   K4  gemm_out_k    : out = o_ws . Wout^T + out_b, same pipelined loop
// ---------------------------------------------------------------------------

typedef __bf16 bf16;
typedef __bf16 bf16x8 __attribute__((ext_vector_type(8)));
typedef __bf16 bf16x4 __attribute__((ext_vector_type(4)));
typedef float  f32x4  __attribute__((ext_vector_type(4)));
typedef __attribute__((address_space(1))) const void* gptr1;
typedef __attribute__((address_space(3))) void*       lptr3;

#define GLL16(g, l) __builtin_amdgcn_global_load_lds((gptr1)(g), (lptr3)(l), 16, 0, 0)
#define MFMA16(a, b, c) __builtin_amdgcn_mfma_f32_16x16x32_bf16(a, b, c, 0, 0, 0)

// ---------------- K1b: fold BN into weights -------------------------------
__global__ __launch_bounds__(256) void build_weights(
    const float* __restrict__ conv_w, const float* __restrict__ conv_b,
    const float* __restrict__ g1, const float* __restrict__ be1,
    const float* __restrict__ mu1, const float* __restrict__ va1,
    const float* __restrict__ down_w, const float* __restrict__ down_b,
    const float* __restrict__ g2, const float* __restrict__ be2,
    const float* __restrict__ mu2, const float* __restrict__ va2,
    const float* __restrict__ out_w,
    bf16* __restrict__ wcat, bf16* __restrict__ wout, float* __restrict__ bias)
{
    int idx = blockIdx.x * 256 + threadIdx.x;
    if (idx < 1536 * 512) {
        int o = idx >> 9, k = idx & 511;
        float s, w;
        if (k < 384) {
            int h = k >> 7, c = k & 127;
            s = g1[o] * rsqrtf(va1[o] + 1e-5f);
            w = conv_w[(h * 1536 + o) * 128 + c];
        } else {
            s = g2[o] * rsqrtf(va2[o] + 1e-5f);
            w = down_w[o * 128 + (k - 384)];
        }
        wcat[idx] = (bf16)(w * s);
    }
    int i2 = idx - 1536 * 512;
    if (i2 >= 0 && i2 < 128 * 512) wout[i2] = (bf16)out_w[i2];
    int i3 = idx - (1536 * 512 + 128 * 512);
    if (i3 >= 0 && i3 < 1536) {
        int o = i3;
        float s1 = g1[o] * rsqrtf(va1[o] + 1e-5f);
        float s2 = g2[o] * rsqrtf(va2[o] + 1e-5f);
        float cb = conv_b[o] + conv_b[1536 + o] + conv_b[2 * 1536 + o];
        bias[o] = cb * s1 + be1[o] - mu1[o] * s1
                + down_b[o] * s2 + be2[o] - mu2[o] * s2;
    }
}

// ---------------- K1: build Zt[48000][512], n = (b*25+v)*120+t ------------
__global__ __launch_bounds__(256) void transform(
    const float* __restrict__ x, const float* __restrict__ A,
    bf16* __restrict__ zt)
{
    __shared__ float xs[25][128];
    const int tid = threadIdx.x;
    const int bt = blockIdx.x;
    const int b = bt / 120, t = bt - b * 120;
    for (int i = tid; i < 25 * 128; i += 256) {
        int u = i >> 7, c = i & 127;
        xs[u][c] = x[((size_t)(b * 25 + u) * 120 + t) * 128 + c];
    }
    __syncthreads();
    const int c = tid & 127, g = tid >> 7;   // g in {0,1}, wave-uniform
    float xr[25];
    #pragma unroll
    for (int u = 0; u < 25; u++) xr[u] = xs[u][c];
    for (int idx = g; idx < 75; idx += 2) {      // (h,v) combos
        int h = idx / 25, v = idx - h * 25;
        const float* Ap = A + (h * 25 + v) * 25;
        float acc = 0.f;
        #pragma unroll
        for (int u = 0; u < 25; u++) acc += Ap[u] * xr[u];
        zt[((size_t)(b * 25 + v) * 120 + t) * 512 + h * 128 + c] = (bf16)acc;
    }
    for (int v = g; v < 25; v += 2)
        zt[((size_t)(b * 25 + v) * 120 + t) * 512 + 384 + c] = (bf16)xs[v][c];
}

// ---------------- K2: QKV GEMM 1536 x 48000 x 512 -------------------------
// 3-buffer 2-deep pipelined K-loop; counted vmcnt(4); raw s_barrier.
// LDS slot swizzle: phys 16B-slot s of row r holds logical slot s^((r>>1)&3);
// staging pre-swizzles the global source (linear LDS dest, rule #21).
// Layouts produced: qg[bh][t][64] (pre-scaled 1/8), kg[bh][t][64],
//                   vtg[bh][dd][128] (cols 120..127 unwritten; zeroed in K3)
__global__ __launch_bounds__(256) void gemm_qkv(
    const bf16* __restrict__ wcat, const bf16* __restrict__ zt,
    const float* __restrict__ bias,
    bf16* __restrict__ qg, bf16* __restrict__ kg, bf16* __restrict__ vtg)
{
    __shared__ __align__(16) char smem[49152];   // 3 x (A 8KB + B 8KB); Lt epi 32KB
    const int tid = threadIdx.x, lane = tid & 63, wv = tid >> 6;
    const int wrow = wv >> 1, wcol = wv & 1;
    // bijective XCD swizzle: same-nt blocks land on one XCD (m204)
    const int NB = 4500, q8 = NB >> 3, r8 = NB & 7;   // 562, 4
    const int xcd = blockIdx.x & 7, sidx = blockIdx.x >> 3;
    const int vid = (xcd < r8 ? xcd * (q8 + 1) : r8 * (q8 + 1) + (xcd - r8) * q8) + sidx;
    const int mt = vid % 12, nt = vid / 12;
    const int colb = lane & 15, rg = lane >> 4;

    f32x4 zz = {0.f, 0.f, 0.f, 0.f};
    f32x4 acc[4][4];
    #pragma unroll
    for (int i = 0; i < 4; i++)
        #pragma unroll
        for (int j = 0; j < 4; j++) acc[i][j] = zz;

    const char* gA = (const char*)wcat + (size_t)mt * 128 * 1024; // 1024B rows
    const char* gB = (const char*)zt + (size_t)nt * 128 * 1024;
    const int srow = lane >> 2;
    const int skb = (((lane & 3) ^ ((lane >> 3) & 3)) * 16);      // inv-swz source
    const int rgs = rg ^ ((colb >> 1) & 3);                       // swz read slot
    const int aoff0 = (wrow * 64 + colb) * 64 + rgs * 16;  // LDS byte offs (64B rows)
    const int boff0 = (wcol * 64 + colb) * 64 + rgs * 16;

    #define STAGE_QKV(kt, b) do {                                              \
        char* As_ = smem + (b) * 16384; char* Bs_ = As_ + 8192;                \
        _Pragma("unroll")                                                      \
        for (int j = 0; j < 2; j++) {                                          \
            int ck = wv * 2 + j;  int row = ck * 16 + srow;                    \
            GLL16(gA + (size_t)row * 1024 + (kt) * 64 + skb, As_ + ck * 1024); \
            GLL16(gB + (size_t)row * 1024 + (kt) * 64 + skb, Bs_ + ck * 1024); \
        } } while (0)

    STAGE_QKV(0, 0);
    STAGE_QKV(1, 1);
    asm volatile("s_waitcnt vmcnt(4)" ::: "memory");   // tile 0 landed
    __builtin_amdgcn_s_barrier();
    for (int kt = 0; kt < 16; kt++) {
        const char* As = smem + (kt % 3) * 16384;
        const char* Bs = As + 8192;
        bf16x8 af[4], bfr[4];
        #pragma unroll
        for (int m = 0; m < 4; m++)
            af[m] = *(const bf16x8*)(As + aoff0 + m * 1024);
        #pragma unroll
        for (int n = 0; n < 4; n++)
            bfr[n] = *(const bf16x8*)(Bs + boff0 + n * 1024);
        int kn = kt + 2;
        STAGE_QKV(kn < 16 ? kn : 15, kn % 3);          // dummy keeps counts fixed
        __builtin_amdgcn_s_setprio(1);
        #pragma unroll
        for (int m = 0; m < 4; m++)
            #pragma unroll
            for (int n = 0; n < 4; n++)
                acc[m][n] = MFMA16(af[m], bfr[n], acc[m][n]);
        __builtin_amdgcn_s_setprio(0);
        asm volatile("s_waitcnt vmcnt(4)" ::: "memory"); // tile kt+1 landed
        __builtin_amdgcn_s_barrier();
    }
    __builtin_amdgcn_sched_barrier(0);

    const int mtb = mt * 128, ntb = nt * 128;
    const int which = mtb >> 9;                  // 0=Q, 1=K, 2=V (block-uniform)

    if (which < 2) {
        // ---- LDS-transpose epilogue: Lt[n'][o'] bf16, XOR-swizzled rows ----
        // Lt uses smem[0..32KB); still-outstanding dummy GLLs target buf2
        // [32KB..48KB) only (buf1 dummies drained by the final vmcnt(4)+barrier).
        bf16* Lt = (bf16*)smem;                  // [128][128] -> 256B rows
        const float qs = (which == 0) ? 0.125f : 1.0f;
        #pragma unroll
        for (int m = 0; m < 4; m++) {
            int o0 = wrow * 64 + m * 16 + rg * 4;
            float b0 = bias[mtb + o0 + 0], b1 = bias[mtb + o0 + 1];
            float b2 = bias[mtb + o0 + 2], b3 = bias[mtb + o0 + 3];
            #pragma unroll
            for (int nn = 0; nn < 4; nn++) {
                int n_ = wcol * 64 + nn * 16 + colb;
                bf16x4 pk;
                pk[0] = (bf16)(fmaxf(acc[m][nn][0] + b0, 0.f) * qs);
                pk[1] = (bf16)(fmaxf(acc[m][nn][1] + b1, 0.f) * qs);
                pk[2] = (bf16)(fmaxf(acc[m][nn][2] + b2, 0.f) * qs);
                pk[3] = (bf16)(fmaxf(acc[m][nn][3] + b3, 0.f) * qs);
                *(bf16x4*)((char*)Lt + n_ * 256 + ((o0 * 2) ^ ((n_ & 7) << 4))) = pk;
            }
        }
        __syncthreads();
        bf16* dst = (which == 0) ? qg : kg;
        #pragma unroll
        for (int i = 0; i < 8; i++) {
            int ch = i * 256 + tid;
            int n_ = ch >> 4, c16 = ch & 15;
            int ng = ntb + n_;
            int grp = ng / 120, t = ng - grp * 120;      // grp = b*25+v
            int o = mtb + c16 * 8;
            int hd = (o >> 6) & 7, dd0 = o & 63;
            bf16x8 vv = *(const bf16x8*)((const char*)Lt + n_ * 256 +
                                         ((c16 * 16) ^ ((n_ & 7) << 4)));
            *(bf16x8*)(dst + ((size_t)(grp * 8 + hd) * 120 + t) * 64 + dd0) = vv;
        }
    } else {
        // ---- V^T direct: t contiguous across colb -> 32B lane-runs ---------
        #pragma unroll
        for (int m = 0; m < 4; m++) {
            #pragma unroll
            for (int reg = 0; reg < 4; reg++) {
                int o = mtb + wrow * 64 + m * 16 + rg * 4 + reg;
                float bo = bias[o];
                int hd = (o >> 6) & 7, dd = o & 63;
                #pragma unroll
                for (int nn = 0; nn < 4; nn++) {
                    int n = ntb + wcol * 64 + nn * 16 + colb;
                    int grp = n / 120, t = n - grp * 120;
                    float val = fmaxf(acc[m][nn][reg] + bo, 0.f);
                    vtg[((size_t)(grp * 8 + hd) * 64 + dd) * 128 + t] = (bf16)val;
                }
            }
        }
    }
    #undef STAGE_QKV
}

// ---------------- K3: causal attention per (b2, head) ---------------------
// LDS 48KB: Vt[16KB] | Ks[16KB] ; Ps[32KB] aliases Ks after QK^T.
__global__ __launch_bounds__(256) void attn_k(
    const bf16* __restrict__ qg, const bf16* __restrict__ kg,
    const bf16* __restrict__ vtg, float* __restrict__ attn_out,
    bf16* __restrict__ og)
{
    __shared__ __align__(16) char sm[49152];
    char* Vt = sm;                // [d][t] 256B rows, XOR-swizzled  (16KB)
    char* Ks = sm + 16384;        // [t][d] 128B rows, XOR-swizzled  (16KB)
    char* Ps = sm + 16384;        // [tq][tk] 256B rows, XOR-swizzled (32KB)
    const int tid = threadIdx.x, lane = tid & 63, wv = tid >> 6;
    const int bh = blockIdx.x;
    const int colb = lane & 15, rg = lane >> 4;

    const char* ksrc = (const char*)kg + (size_t)bh * 15360;
    const char* vsrc = (const char*)vtg + (size_t)bh * 16384;
    #pragma unroll
    for (int is = 0; is < 4; is++) {
        int cb = is * 256 + wv * 64;             // wave-uniform chunk base
        if (cb < 960) {
            int bb = (cb + lane) * 16;
            int row = bb >> 7;
            int gsrc = (bb & ~127) | ((bb & 127) ^ ((row & 7) << 4));
            GLL16(ksrc + gsrc, Ks + cb * 16);
        }
        {
            int bb = (cb + lane) * 16;
            int row = bb >> 8;
            int gsrc = (bb & ~255) | ((bb & 255) ^ ((row & 7) << 4));
            GLL16(vsrc + gsrc, Vt + cb * 16);
        }
    }
    const char* qsrc = (const char*)qg + (size_t)bh * 15360;
    bf16x8 qf[2][2];
    #pragma unroll
    for (int kk = 0; kk < 2; kk++)
        #pragma unroll
        for (int m = 0; m < 2; m++) {
            int row = wv * 32 + m * 16 + colb;
            qf[kk][m] = *(const bf16x8*)(qsrc + (size_t)row * 128 + rg * 16 + kk * 64);
        }
    asm volatile("s_waitcnt vmcnt(0)" ::: "memory");
    __syncthreads();
    {
        f32x4 z = {0.f, 0.f, 0.f, 0.f};
        if (tid < 64) {
            int r = 120 + (tid >> 3), off = (tid & 7) * 16;
            *(f32x4*)(Ks + r * 128 + off) = z;
        } else if (tid < 128) {
            int d = tid - 64;
            *(f32x4*)(Vt + d * 256 + (240 ^ ((d & 7) << 4))) = z;
        }
    }
    __syncthreads();

    // S = Q.K^T (q pre-scaled by 1/8 in K2)
    f32x4 accs[2][8];
    #pragma unroll
    for (int m = 0; m < 2; m++)
        #pragma unroll
        for (int ct = 0; ct < 8; ct++) accs[m][ct] = (f32x4){0.f, 0.f, 0.f, 0.f};
    #pragma unroll
    for (int kk = 0; kk < 2; kk++) {
        #pragma unroll
        for (int ct = 0; ct < 8; ct++) {
            int rk = ct * 16 + colb;
            int byo = rk * 128 + ((rg * 16 + kk * 64) ^ ((rk & 7) << 4));
            bf16x8 bk = *(const bf16x8*)(Ks + byo);
            accs[0][ct] = MFMA16(qf[kk][0], bk, accs[0][ct]);
            accs[1][ct] = MFMA16(qf[kk][1], bk, accs[1][ct]);
        }
    }
    __syncthreads();   // Ks dead; Ps may now overwrite it

    // causal softmax; write attn fp32 to d_out, P bf16 to LDS
    const int rqb = wv * 32;
    float* attn_base = attn_out + (size_t)bh * 120 * 120;
    #pragma unroll
    for (int m = 0; m < 2; m++) {
        #pragma unroll
        for (int reg = 0; reg < 4; reg++) {
            int t_q = rqb + m * 16 + rg * 4 + reg;
            float s[8], mx = -1e30f;
            #pragma unroll
            for (int ct = 0; ct < 8; ct++) {
                int col = ct * 16 + colb;
                bool valid = (col <= t_q) && (col < 120);
                s[ct] = valid ? accs[m][ct][reg] : -1e30f;
                mx = fmaxf(mx, s[ct]);
            }
            #pragma unroll
            for (int d = 1; d < 16; d <<= 1) mx = fmaxf(mx, __shfl_xor(mx, d, 64));
            float p[8], sum = 0.f;
            #pragma unroll
            for (int ct = 0; ct < 8; ct++) {
                p[ct] = (s[ct] > -1e29f) ? __expf(s[ct] - mx) : 0.f;
                sum += p[ct];
            }
            #pragma unroll
            for (int d = 1; d < 16; d <<= 1) sum += __shfl_xor(sum, d, 64);
            float inv = 1.f / sum;
            if (t_q < 120) {
                float* orow = attn_base + (size_t)t_q * 120;
                #pragma unroll
                for (int ct = 0; ct < 8; ct++) {
                    int col = ct * 16 + colb;
                    if (col < 120) orow[col] = p[ct] * inv;
                }
            }
            #pragma unroll
            for (int ct = 0; ct < 8; ct++) {
                int col = ct * 16 + colb;
                int byo = t_q * 256 + ((col * 2) ^ ((t_q & 7) << 4));
                *(bf16*)(Ps + byo) = (bf16)(p[ct] * inv);
            }
        }
    }
    __syncthreads();

    // O = P.V ; causal skip: P rows of wave wv have zero cols >= 32*(wv+1)
    f32x4 acco[2][4];
    #pragma unroll
    for (int m = 0; m < 2; m++)
        #pragma unroll
        for (int dt = 0; dt < 4; dt++) acco[m][dt] = (f32x4){0.f, 0.f, 0.f, 0.f};
    for (int kk = 0; kk <= wv; kk++) {
        bf16x8 ap[2];
        #pragma unroll
        for (int m = 0; m < 2; m++) {
            int row = rqb + m * 16 + colb;
            int byo = row * 256 + ((rg * 16 + kk * 64) ^ ((row & 7) << 4));
            ap[m] = *(const bf16x8*)(Ps + byo);
        }
        #pragma unroll
        for (int dt = 0; dt < 4; dt++) {
            int rd = dt * 16 + colb;
            int byo = rd * 256 + ((rg * 16 + kk * 64) ^ ((rd & 7) << 4));
            bf16x8 bv = *(const bf16x8*)(Vt + byo);
            acco[0][dt] = MFMA16(ap[0], bv, acco[0][dt]);
            acco[1][dt] = MFMA16(ap[1], bv, acco[1][dt]);
        }
    }
    const int b2 = bh >> 3, h = bh & 7;
    #pragma unroll
    for (int m = 0; m < 2; m++)
        #pragma unroll
        for (int dt = 0; dt < 4; dt++)
            #pragma unroll
            for (int reg = 0; reg < 4; reg++) {
                int t = rqb + m * 16 + rg * 4 + reg;
                if (t < 120) {
                    int dfull = h * 64 + dt * 16 + colb;
                    og[((size_t)b2 * 120 + t) * 512 + dfull] = (bf16)acco[m][dt][reg];
                }
            }
}

// ---------------- K4: out = o . Wout^T + out_b  (48000 x 128 x 512) -------
__global__ __launch_bounds__(256) void gemm_out_k(
    const bf16* __restrict__ og, const bf16* __restrict__ wout,
    const float* __restrict__ outb, float* __restrict__ out)
{
    __shared__ __align__(16) char smem[49152];
    const int tid = threadIdx.x, lane = tid & 63, wv = tid >> 6;
    const int wrow = wv >> 1, wcol = wv & 1;
    const int nt = blockIdx.x;
    const int colb = lane & 15, rg = lane >> 4;

    f32x4 zz = {0.f, 0.f, 0.f, 0.f};
    f32x4 acc[4][4];
    #pragma unroll
    for (int i = 0; i < 4; i++)
        #pragma unroll
        for (int j = 0; j < 4; j++) acc[i][j] = zz;

    const char* gA = (const char*)og + (size_t)nt * 128 * 1024;
    const char* gB = (const char*)wout;
    const int srow = lane >> 2;
    const int skb = (((lane & 3) ^ ((lane >> 3) & 3)) * 16);
    const int rgs = rg ^ ((colb >> 1) & 3);
    const int aoff0 = (wrow * 64 + colb) * 64 + rgs * 16;
    const int boff0 = (wcol * 64 + colb) * 64 + rgs * 16;

    #define STAGE_OUT(kt, b) do {                                              \
        char* As_ = smem + (b) * 16384; char* Bs_ = As_ + 8192;                \
        _Pragma("unroll")                                                      \
        for (int j = 0; j < 2; j++) {                                          \
            int ck = wv * 2 + j;  int row = ck * 16 + srow;                    \
            GLL16(gA + (size_t)row * 1024 + (kt) * 64 + skb, As_ + ck * 1024); \
            GLL16(gB + (size_t)row * 1024 + (kt) * 64 + skb, Bs_ + ck * 1024); \
        } } while (0)

    STAGE_OUT(0, 0);
    STAGE_OUT(1, 1);
    asm volatile("s_waitcnt vmcnt(4)" ::: "memory");
    __builtin_amdgcn_s_barrier();
    for (int kt = 0; kt < 16; kt++) {
        const char* As = smem + (kt % 3) * 16384;
        const char* Bs = As + 8192;
        bf16x8 af[4], bfr[4];
        #pragma unroll
        for (int m = 0; m < 4; m++)
            af[m] = *(const bf16x8*)(As + aoff0 + m * 1024);
        #pragma unroll
        for (int n = 0; n < 4; n++)
            bfr[n] = *(const bf16x8*)(Bs + boff0 + n * 1024);
        int kn = kt + 2;
        STAGE_OUT(kn < 16 ? kn : 15, kn % 3);
        __builtin_amdgcn_s_setprio(1);
        #pragma unroll
        for (int m = 0; m < 4; m++)
            #pragma unroll
            for (int n = 0; n < 4; n++)
                acc[m][n] = MFMA16(af[m], bfr[n], acc[m][n]);
        __builtin_amdgcn_s_setprio(0);
        asm volatile("s_waitcnt vmcnt(4)" ::: "memory");
        __builtin_amdgcn_s_barrier();
    }
    __builtin_amdgcn_sched_barrier(0);

    const int rbase = nt * 128 + wrow * 64;
    #pragma unroll
    for (int m = 0; m < 4; m++)
        #pragma unroll
        for (int reg = 0; reg < 4; reg++) {
            int r = rbase + m * 16 + rg * 4 + reg;
            #pragma unroll
            for (int nn = 0; nn < 4; nn++) {
                int c = wcol * 64 + nn * 16 + colb;
                out[(size_t)r * 128 + c] = acc[m][nn][reg] + outb[c];
            }
        }
    #undef STAGE_OUT
}

// ---------------- launch ---------------------------------------------------
extern "C" void kernel_launch(void* const* d_in, const int* in_sizes, int n_in,
                              void* d_out, int out_size, void* d_ws, size_t ws_size,
                              hipStream_t stream)
{
    (void)in_sizes; (void)n_in; (void)out_size; (void)ws_size;
    const float* x      = (const float*)d_in[0];
    const float* A      = (const float*)d_in[1];
    const float* conv_w = (const float*)d_in[2];
    const float* conv_b = (const float*)d_in[3];
    const float* bn_g   = (const float*)d_in[4];
    const float* bn_b   = (const float*)d_in[5];
    const float* bn_m   = (const float*)d_in[6];
    const float* bn_v   = (const float*)d_in[7];
    const float* dw     = (const float*)d_in[8];
    const float* db     = (const float*)d_in[9];
    const float* dg     = (const float*)d_in[10];
    const float* dbb    = (const float*)d_in[11];
    const float* dm     = (const float*)d_in[12];
    const float* dvv    = (const float*)d_in[13];
    const float* out_w  = (const float*)d_in[14];
    const float* out_b  = (const float*)d_in[15];

    char* ws = (char*)d_ws;
    const size_t OFF_WCAT = 0;                       // 1536*512*2   = 1,572,864
    const size_t OFF_WOUT = 1572864;                 // 128*512*2    =   131,072
    const size_t OFF_BIAS = 1703936;                 // 1536*4       =     6,144
    const size_t OFF_ZT   = 1710080;                 // 48000*512*2  = 49,152,000
    const size_t OFF_Q    = 50862080;                // 3200*120*64*2= 49,152,000
    const size_t OFF_K    = 100014080;               // 49,152,000
    const size_t OFF_VT   = 149166080;               // 3200*64*128*2= 52,428,800
    const size_t OFF_O    = OFF_ZT;                  // reuse Zt region after K2

    bf16*  wcat = (bf16*)(ws + OFF_WCAT);
    bf16*  wout = (bf16*)(ws + OFF_WOUT);
    float* bias = (float*)(ws + OFF_BIAS);
    bf16*  zt   = (bf16*)(ws + OFF_ZT);
    bf16*  qg   = (bf16*)(ws + OFF_Q);
    bf16*  kg   = (bf16*)(ws + OFF_K);
    bf16*  vtg  = (bf16*)(ws + OFF_VT);
    bf16*  og   = (bf16*)(ws + OFF_O);
    float* outp = (float*)d_out;
    float* attn = outp + 6144000;                    // out (400,120,128) first

    build_weights<<<3334, 256, 0, stream>>>(conv_w, conv_b, bn_g, bn_b, bn_m, bn_v,
                                            dw, db, dg, dbb, dm, dvv, out_w,
                                            wcat, wout, bias);
    transform<<<1920, 256, 0, stream>>>(x, A, zt);
    gemm_qkv<<<4500, 256, 0, stream>>>(wcat, zt, bias, qg, kg, vtg);
    attn_k<<<3200, 256, 0, stream>>>(qg, kg, vtg, attn, og);
    gemm_out_k<<<375, 256, 0, stream>>>(og, wout, out_b, outp);
}